// Round 5
// baseline (477.662 us; speedup 1.0000x reference)
//
#include <hip/hip_runtime.h>

#define BSZ 256
#define SEQ 2048
#define NT  64
#define KS  5.0f

typedef __fp16 half2_t __attribute__((ext_vector_type(2)));

static __device__ __forceinline__ float wave_red_max(float x) {
#pragma unroll
    for (int d = 1; d < 64; d <<= 1) x = fmaxf(x, __shfl_xor(x, d));
    return x;
}
static __device__ __forceinline__ float wave_red_sum(float x) {
#pragma unroll
    for (int d = 1; d < 64; d <<= 1) x += __shfl_xor(x, d);
    return x;
}

// ---------------------------------------------------------------------------
// Forward algorithm in exp-domain, one batch per 64-thread (1-wave) block.
// Lane j owns tag j. b[j] = exp(alpha[j] - C), C wave-uniform log-scale.
// Per step: lane-pair packing via DPP quad_perm (VALU, no LDS pipe), then
// 32 grouped v_readlane broadcasts (SGPR), then 32 v_dot2_f32_f16 over the
// f16 E-pair table (32 VGPRs). Emissions pre-shifted by KS; lazy renorm /8.
// ---------------------------------------------------------------------------
__global__ __launch_bounds__(64) void crf_forward_kernel(
    const float* __restrict__ logits,
    const int*   __restrict__ tags,
    const int*   __restrict__ mask,
    const float* __restrict__ trans,
    const float* __restrict__ startT,
    const float* __restrict__ endT,
    float* __restrict__ den_out,
    float* __restrict__ numemit_out)
{
    const int b = blockIdx.x;
    const int j = threadIdx.x;
    const float* __restrict__ L  = logits + (size_t)b * SEQ * NT;
    const int*   __restrict__ tg = tags + (size_t)b * SEQ;
    const int*   __restrict__ mk = mask + (size_t)b * SEQ;

    // E pairs: Epair[i] = (exp(trans[2i][j]), exp(trans[2i+1][j])) as f16x2
    half2_t Epair[NT / 2];
#pragma unroll
    for (int i = 0; i < NT / 2; ++i) {
        float e0 = __expf(trans[(2 * i + 0) * NT + j]);
        float e1 = __expf(trans[(2 * i + 1) * NT + j]);
        Epair[i] = __builtin_amdgcn_cvt_pkrtz(e0, e1);
    }

    // ---- t = 0 ----
    float em0  = L[j];
    int   m0   = mk[0];
    int   tag0 = tg[0] * m0;
    float alpha0 = startT[j] + em0;
    float C  = wave_red_max(alpha0);
    float bj = __expf(alpha0 - C);
    float numacc = (m0 && j == tag0) ? em0 : 0.0f;

    auto STEP = [&](int t, float em, float F, int mt, int tagt) {
        // neighbor via DPP quad_perm [1,0,3,2] == lane ^ 1 (pure VALU)
        int   bji = __builtin_bit_cast(int, bj);
        int   nbi = __builtin_amdgcn_update_dpp(0, bji, 0xB1, 0xF, 0xF, true);
        float nb  = __builtin_bit_cast(float, nbi);
        // even lane 2i now packs (b[2i], b[2i+1]); odd lanes pack swapped
        half2_t hp  = __builtin_amdgcn_cvt_pkrtz(bj, nb);
        int     hpi = __builtin_bit_cast(int, hp);

        // grouped broadcasts: 32 independent readlanes (even lanes only)
        int rls[NT / 2];
#pragma unroll
        for (int i = 0; i < NT / 2; ++i)
            rls[i] = __builtin_amdgcn_readlane(hpi, 2 * i);

        // 8 independent accumulator chains of 4 dot2 each
        float a0 = 0.f, a1 = 0.f, a2 = 0.f, a3 = 0.f;
        float a4 = 0.f, a5 = 0.f, a6 = 0.f, a7 = 0.f;
#pragma unroll
        for (int i = 0; i < NT / 2; i += 8) {
            a0 = __builtin_amdgcn_fdot2(__builtin_bit_cast(half2_t, rls[i + 0]), Epair[i + 0], a0, false);
            a1 = __builtin_amdgcn_fdot2(__builtin_bit_cast(half2_t, rls[i + 1]), Epair[i + 1], a1, false);
            a2 = __builtin_amdgcn_fdot2(__builtin_bit_cast(half2_t, rls[i + 2]), Epair[i + 2], a2, false);
            a3 = __builtin_amdgcn_fdot2(__builtin_bit_cast(half2_t, rls[i + 3]), Epair[i + 3], a3, false);
            a4 = __builtin_amdgcn_fdot2(__builtin_bit_cast(half2_t, rls[i + 4]), Epair[i + 4], a4, false);
            a5 = __builtin_amdgcn_fdot2(__builtin_bit_cast(half2_t, rls[i + 5]), Epair[i + 5], a5, false);
            a6 = __builtin_amdgcn_fdot2(__builtin_bit_cast(half2_t, rls[i + 6]), Epair[i + 6], a6, false);
            a7 = __builtin_amdgcn_fdot2(__builtin_bit_cast(half2_t, rls[i + 7]), Epair[i + 7], a7, false);
        }
        float s = ((a0 + a1) + (a2 + a3)) + ((a4 + a5) + (a6 + a7));
        float bnew = s * F;
        bj = mt ? bnew : bj;
        C  = mt ? C + KS : C;
        numacc += (mt && j == tagt && t < SEQ - 1) ? em : 0.0f;
    };

    // ---- prefetch block t0 = 8 ----
    float emN[8];
    {
        const float* Lp = L + 8 * NT + j;
#pragma unroll
        for (int u = 0; u < 8; ++u) emN[u] = Lp[u * NT];
    }
    int4 mN0 = *(const int4*)(mk + 8);
    int4 mN1 = *(const int4*)(mk + 12);
    int4 tN0 = *(const int4*)(tg + 8);
    int4 tN1 = *(const int4*)(tg + 12);

    // ---- peel t = 1..7 ----
#pragma unroll
    for (int t = 1; t < 8; ++t) {
        float em = L[t * NT + j];
        float F  = __expf(em - KS);
        int   mt = mk[t];
        int   tagt = tg[t] * mt;
        STEP(t, em, F, mt, tagt);
    }
    float rnv = bj;   // renorm snapshot

    // ---- main loop: blocks of 8 steps, t = 8..2047 ----
    for (int t0 = 8; t0 < SEQ; t0 += 8) {
        float e0 = emN[0], e1 = emN[1], e2 = emN[2], e3 = emN[3];
        float e4 = emN[4], e5 = emN[5], e6 = emN[6], e7 = emN[7];
        int mt0 = mN0.x, mt1 = mN0.y, mt2 = mN0.z, mt3 = mN0.w;
        int mt4 = mN1.x, mt5 = mN1.y, mt6 = mN1.z, mt7 = mN1.w;
        int tg0_ = tN0.x * mt0, tg1_ = tN0.y * mt1, tg2_ = tN0.z * mt2, tg3_ = tN0.w * mt3;
        int tg4_ = tN1.x * mt4, tg5_ = tN1.y * mt5, tg6_ = tN1.z * mt6, tg7_ = tN1.w * mt7;

        int tn = t0 + 8;
        if (tn > SEQ - 8) tn = SEQ - 8;
        {
            const float* Lq = L + tn * NT + j;
#pragma unroll
            for (int u = 0; u < 8; ++u) emN[u] = Lq[u * NT];
        }
        mN0 = *(const int4*)(mk + tn);
        mN1 = *(const int4*)(mk + tn + 4);
        tN0 = *(const int4*)(tg + tn);
        tN1 = *(const int4*)(tg + tn + 4);

        // lazy renorm reduce (off the b-chain; applied after 2 steps)
        float mx = wave_red_max(rnv);

        float F0 = __expf(e0 - KS), F1 = __expf(e1 - KS);
        float F2 = __expf(e2 - KS), F3 = __expf(e3 - KS);
        float F4 = __expf(e4 - KS), F5 = __expf(e5 - KS);
        float F6 = __expf(e6 - KS), F7 = __expf(e7 - KS);

        STEP(t0 + 0, e0, F0, mt0, tg0_);
        STEP(t0 + 1, e1, F1, mt1, tg1_);
        bj = bj / mx;          // exact uniform rescale
        C += __logf(mx);
        STEP(t0 + 2, e2, F2, mt2, tg2_);
        STEP(t0 + 3, e3, F3, mt3, tg3_);
        STEP(t0 + 4, e4, F4, mt4, tg4_);
        STEP(t0 + 5, e5, F5, mt5, tg5_);
        STEP(t0 + 6, e6, F6, mt6, tg6_);
        STEP(t0 + 7, e7, F7, mt7, tg7_);
        rnv = bj;
    }

    // ---- finalize ----
    float v = bj * __expf(endT[j]);
    v      = wave_red_sum(v);
    numacc = wave_red_sum(numacc);
    if (j == 0) {
        den_out[b]     = C + __logf(v);
        numemit_out[b] = numacc;
    }
}

// ---------------------------------------------------------------------------
// Numerator transition/start/end terms + last emission term.
// ---------------------------------------------------------------------------
__global__ __launch_bounds__(256) void crf_numer_kernel(
    const float* __restrict__ logits,
    const int*   __restrict__ tags,
    const int*   __restrict__ mask,
    const float* __restrict__ trans,
    const float* __restrict__ startT,
    const float* __restrict__ endT,
    float* __restrict__ numtrans_out)
{
    const int b   = blockIdx.x;
    const int tid = threadIdx.x;

    __shared__ float st[NT * NT];
    __shared__ float redf[256];
    __shared__ int   redi[256];

    for (int i = tid; i < NT * NT; i += 256) st[i] = trans[i];
    __syncthreads();

    const int* __restrict__ tg = tags + (size_t)b * SEQ;
    const int* __restrict__ mk = mask + (size_t)b * SEQ;

    float acc = 0.0f;
    int   cnt = 0;
    for (int t = tid; t < SEQ; t += 256) {
        int mt = mk[t];
        cnt += mt;
        if (t < SEQ - 1) {
            int m1 = mk[t + 1];
            int a  = tg[t]     * mt;
            int c  = tg[t + 1] * m1;
            acc += st[a * NT + c] * (float)m1;
        }
    }
    redf[tid] = acc;
    redi[tid] = cnt;
    __syncthreads();
    for (int off = 128; off > 0; off >>= 1) {
        if (tid < off) {
            redf[tid] += redf[tid + off];
            redi[tid] += redi[tid + off];
        }
        __syncthreads();
    }

    if (tid == 0) {
        int   last_idx = redi[0] - 1;
        int   m_last   = mk[SEQ - 1];
        int   tag0     = tg[0] * mk[0];
        int   last_tag = tg[last_idx] * mk[last_idx];
        float r = redf[0] + startT[tag0] + endT[last_tag];
        r += logits[((size_t)b * SEQ + (SEQ - 1)) * NT + last_tag] * (float)m_last;
        numtrans_out[b] = r;
    }
}

// ---------------------------------------------------------------------------
// Final scalar reduction: out = sum_b (numerator - denominator).
// ---------------------------------------------------------------------------
__global__ __launch_bounds__(256) void crf_reduce_kernel(
    const float* __restrict__ den,
    const float* __restrict__ numemit,
    const float* __restrict__ numtrans,
    float* __restrict__ out)
{
    __shared__ float red[256];
    const int tid = threadIdx.x;
    red[tid] = numemit[tid] + numtrans[tid] - den[tid];
    __syncthreads();
    for (int off = 128; off > 0; off >>= 1) {
        if (tid < off) red[tid] += red[tid + off];
        __syncthreads();
    }
    if (tid == 0) out[0] = red[0];
}

// ---------------------------------------------------------------------------
extern "C" void kernel_launch(void* const* d_in, const int* in_sizes, int n_in,
                              void* d_out, int out_size, void* d_ws, size_t ws_size,
                              hipStream_t stream)
{
    const float* logits = (const float*)d_in[0];
    const int*   tags   = (const int*)  d_in[1];
    const int*   mask   = (const int*)  d_in[2];
    const float* trans  = (const float*)d_in[3];
    const float* startT = (const float*)d_in[4];
    const float* endT   = (const float*)d_in[5];
    float* out = (float*)d_out;

    float* den      = (float*)d_ws;
    float* numemit  = den + BSZ;
    float* numtrans = den + 2 * BSZ;

    crf_forward_kernel<<<BSZ, 64, 0, stream>>>(logits, tags, mask, trans,
                                               startT, endT, den, numemit);
    crf_numer_kernel<<<BSZ, 256, 0, stream>>>(logits, tags, mask, trans,
                                              startT, endT, numtrans);
    crf_reduce_kernel<<<1, 256, 0, stream>>>(den, numemit, numtrans, out);
}

// Round 6
// 210.425 us; speedup vs baseline: 2.2700x; 2.2700x over previous
//
#include <hip/hip_runtime.h>

#define BSZ 256
#define SEQ 2048
#define NT  64
#define NC  16      // chunks per sequence
#define CL  128     // D-steps per chunk (chunk 0: init + 127)
#define KS  5.0f

typedef __fp16 half2_t __attribute__((ext_vector_type(2)));

static __device__ __forceinline__ float wave_red_max(float x) {
#pragma unroll
    for (int d = 1; d < 64; d <<= 1) x = fmaxf(x, __shfl_xor(x, d));
    return x;
}
static __device__ __forceinline__ float wave_red_sum(float x) {
#pragma unroll
    for (int d = 1; d < 64; d <<= 1) x += __shfl_xor(x, d);
    return x;
}

// y = sum over all 64 lanes' x of (pairwise f16 dot with Ep table).
// Even lane 2i packs (x[2i], x[2i+1]) via DPP quad_perm; readlane broadcasts.
static __device__ __forceinline__ float dot_bcast(float x, const half2_t* Ep) {
    int xi = __builtin_bit_cast(int, x);
    int ni = __builtin_amdgcn_update_dpp(0, xi, 0xB1, 0xF, 0xF, true); // lane^1
    half2_t hp  = __builtin_amdgcn_cvt_pkrtz(x, __builtin_bit_cast(float, ni));
    int     hpi = __builtin_bit_cast(int, hp);
    float a0 = 0.f, a1 = 0.f, a2 = 0.f, a3 = 0.f;
    float a4 = 0.f, a5 = 0.f, a6 = 0.f, a7 = 0.f;
#pragma unroll
    for (int i = 0; i < NT / 2; i += 8) {
        a0 = __builtin_amdgcn_fdot2(__builtin_bit_cast(half2_t, __builtin_amdgcn_readlane(hpi, 2 * (i + 0))), Ep[i + 0], a0, false);
        a1 = __builtin_amdgcn_fdot2(__builtin_bit_cast(half2_t, __builtin_amdgcn_readlane(hpi, 2 * (i + 1))), Ep[i + 1], a1, false);
        a2 = __builtin_amdgcn_fdot2(__builtin_bit_cast(half2_t, __builtin_amdgcn_readlane(hpi, 2 * (i + 2))), Ep[i + 2], a2, false);
        a3 = __builtin_amdgcn_fdot2(__builtin_bit_cast(half2_t, __builtin_amdgcn_readlane(hpi, 2 * (i + 3))), Ep[i + 3], a3, false);
        a4 = __builtin_amdgcn_fdot2(__builtin_bit_cast(half2_t, __builtin_amdgcn_readlane(hpi, 2 * (i + 4))), Ep[i + 4], a4, false);
        a5 = __builtin_amdgcn_fdot2(__builtin_bit_cast(half2_t, __builtin_amdgcn_readlane(hpi, 2 * (i + 5))), Ep[i + 5], a5, false);
        a6 = __builtin_amdgcn_fdot2(__builtin_bit_cast(half2_t, __builtin_amdgcn_readlane(hpi, 2 * (i + 6))), Ep[i + 6], a6, false);
        a7 = __builtin_amdgcn_fdot2(__builtin_bit_cast(half2_t, __builtin_amdgcn_readlane(hpi, 2 * (i + 7))), Ep[i + 7], a7, false);
    }
    return ((a0 + a1) + (a2 + a3)) + ((a4 + a5) + (a6 + a7));
}

// ---------------------------------------------------------------------------
// Pass 1: per (batch, chunk) block of 2 waves.
// Wave 0: forward run. Chunk 0 starts from true init (exact); chunks >=1 from
//         ones. Applies D_t = E·diag(F_t) for t in [max(1,128c), 128c+127].
//         Tracks Cf (log scale); fuses numerator emission gather for its t's.
// Wave 1: backward run (chunks >=1): w = D_t·w from t=128c+127 down to 128c,
//         starting from ones. Scale cancels in glue; renorm by max only.
// Rank-1 contraction makes M_c ≈ w_c r_c^T / sum(w_c) exact at f32 (kappa^128).
// ---------------------------------------------------------------------------
__global__ __launch_bounds__(128) void crf_pass1_kernel(
    const float* __restrict__ logits,
    const int*   __restrict__ tags,
    const int*   __restrict__ mask,
    const float* __restrict__ trans,
    const float* __restrict__ startT,
    float* __restrict__ rbuf,    // [BSZ][NC][NT]
    float* __restrict__ wbuf,    // [BSZ][NC][NT] (slot 0 unused)
    float* __restrict__ Cf,      // [BSZ][NC]
    float* __restrict__ numem)   // [BSZ][NC]
{
    const int blk   = blockIdx.x;
    const int batch = blk >> 4;
    const int c     = blk & (NC - 1);
    const int wave  = threadIdx.x >> 6;
    const int j     = threadIdx.x & 63;

    const float* __restrict__ L  = logits + (size_t)batch * SEQ * NT;
    const int*   __restrict__ tg = tags + (size_t)batch * SEQ;
    const int*   __restrict__ mk = mask + (size_t)batch * SEQ;

    if (wave == 0) {
        // ---------------- forward run ----------------
        // E columns as f16 pairs: Ep[k] = (E[2k][j], E[2k+1][j])
        half2_t Ep[NT / 2];
#pragma unroll
        for (int k = 0; k < NT / 2; ++k) {
            float e0 = __expf(trans[(2 * k + 0) * NT + j]);
            float e1 = __expf(trans[(2 * k + 1) * NT + j]);
            Ep[k] = __builtin_amdgcn_cvt_pkrtz(e0, e1);
        }

        float bj, C, numacc = 0.0f;
        int   t0, len;
        if (c == 0) {
            float em0  = L[j];
            int   m0   = mk[0];
            int   tag0 = tg[0] * m0;
            float alpha0 = startT[j] + em0;
            C  = wave_red_max(alpha0);
            bj = __expf(alpha0 - C);
            numacc = (m0 && j == tag0) ? em0 : 0.0f;
            t0 = 1; len = CL - 1;
        } else {
            bj = 1.0f; C = 0.0f;
            t0 = c * CL; len = CL;
        }

        float em = L[t0 * NT + j];   // prefetch first
        for (int s = 0; s < len; ++s) {
            int   t      = t0 + s;
            float em_cur = em;
            if (s + 1 < len) em = L[(t + 1) * NT + j];
            int   mt   = mk[t];
            int   tagt = tg[t] * mt;
            float F    = __expf(em_cur - KS);

            float sdot = dot_bcast(bj, Ep);
            float bnew = sdot * F;
            if (mt) { bj = bnew; C += KS; }
            numacc += (mt && j == tagt && t < SEQ - 1) ? em_cur : 0.0f;

            if ((s & 7) == 7) {
                float mx = wave_red_max(bj);
                bj = bj / mx;
                C += __logf(mx);
            }
        }

        rbuf[((size_t)batch * NC + c) * NT + j] = bj;
        float ns = wave_red_sum(numacc);
        if (j == 0) {
            Cf[batch * NC + c]    = C;
            numem[batch * NC + c] = ns;
        }
    } else if (c > 0) {
        // ---------------- backward run ----------------
        // E rows as f16 pairs: Ep[k] = (E[j][2k], E[j][2k+1]) (contiguous)
        half2_t Ep[NT / 2];
#pragma unroll
        for (int k = 0; k < NT / 2; ++k) {
            float e0 = __expf(trans[j * NT + 2 * k + 0]);
            float e1 = __expf(trans[j * NT + 2 * k + 1]);
            Ep[k] = __builtin_amdgcn_cvt_pkrtz(e0, e1);
        }

        float wj = 1.0f;
        const int thi = c * CL + CL - 1;
        float em = L[thi * NT + j];   // prefetch first
        for (int s = 0; s < CL; ++s) {
            int   t      = thi - s;
            float em_cur = em;
            if (s + 1 < CL) em = L[(t - 1) * NT + j];
            int   mt = mk[t];
            float F  = __expf(em_cur - KS);

            float g    = F * wj;              // diag(F)·w
            float wnew = dot_bcast(g, Ep);    // E·g
            if (mt) wj = wnew;

            if ((s & 7) == 7) {
                float mx = wave_red_max(wj);
                wj = wj / mx;
            }
        }
        wbuf[((size_t)batch * NC + c) * NT + j] = wj;
    }
}

// ---------------------------------------------------------------------------
// Glue: per batch, combine chunk vectors into log-denominator; sum numem.
// log Z = sum Cf + sum_{c>=1}[log(r_{c-1}.w_c) - log(sum w_c)] + log(r_15.f)
// ---------------------------------------------------------------------------
__global__ __launch_bounds__(64) void crf_glue_kernel(
    const float* __restrict__ rbuf,
    const float* __restrict__ wbuf,
    const float* __restrict__ Cf,
    const float* __restrict__ numem,
    const float* __restrict__ endT,
    float* __restrict__ den_out,
    float* __restrict__ numemit_out)
{
    const int batch = blockIdx.x;
    const int j     = threadIdx.x;

    const float* rb = rbuf + (size_t)batch * NC * NT;
    const float* wb = wbuf + (size_t)batch * NC * NT;

    float cfsum  = (j < NC) ? Cf[batch * NC + j] : 0.0f;
    float numsum = (j < NC) ? numem[batch * NC + j] : 0.0f;
    cfsum  = wave_red_sum(cfsum);
    numsum = wave_red_sum(numsum);

    float den = cfsum;
#pragma unroll
    for (int c = 1; c < NC; ++c) {
        float rprev = rb[(c - 1) * NT + j];
        float wc    = wb[c * NT + j];
        float dot = wave_red_sum(rprev * wc);
        float rho = wave_red_sum(wc);
        den += __logf(dot) - __logf(rho);
    }
    float fin = wave_red_sum(rb[(NC - 1) * NT + j] * __expf(endT[j]));
    den += __logf(fin);

    if (j == 0) {
        den_out[batch]     = den;
        numemit_out[batch] = numsum;
    }
}

// ---------------------------------------------------------------------------
// Numerator transition/start/end terms + last emission term.
// ---------------------------------------------------------------------------
__global__ __launch_bounds__(256) void crf_numer_kernel(
    const float* __restrict__ logits,
    const int*   __restrict__ tags,
    const int*   __restrict__ mask,
    const float* __restrict__ trans,
    const float* __restrict__ startT,
    const float* __restrict__ endT,
    float* __restrict__ numtrans_out)
{
    const int b   = blockIdx.x;
    const int tid = threadIdx.x;

    __shared__ float st[NT * NT];
    __shared__ float redf[256];
    __shared__ int   redi[256];

    for (int i = tid; i < NT * NT; i += 256) st[i] = trans[i];
    __syncthreads();

    const int* __restrict__ tg = tags + (size_t)b * SEQ;
    const int* __restrict__ mk = mask + (size_t)b * SEQ;

    float acc = 0.0f;
    int   cnt = 0;
    for (int t = tid; t < SEQ; t += 256) {
        int mt = mk[t];
        cnt += mt;
        if (t < SEQ - 1) {
            int m1 = mk[t + 1];
            int a  = tg[t]     * mt;
            int c  = tg[t + 1] * m1;
            acc += st[a * NT + c] * (float)m1;
        }
    }
    redf[tid] = acc;
    redi[tid] = cnt;
    __syncthreads();
    for (int off = 128; off > 0; off >>= 1) {
        if (tid < off) {
            redf[tid] += redf[tid + off];
            redi[tid] += redi[tid + off];
        }
        __syncthreads();
    }

    if (tid == 0) {
        int   last_idx = redi[0] - 1;
        int   m_last   = mk[SEQ - 1];
        int   tag0     = tg[0] * mk[0];
        int   last_tag = tg[last_idx] * mk[last_idx];
        float r = redf[0] + startT[tag0] + endT[last_tag];
        r += logits[((size_t)b * SEQ + (SEQ - 1)) * NT + last_tag] * (float)m_last;
        numtrans_out[b] = r;
    }
}

// ---------------------------------------------------------------------------
// Final scalar reduction: out = sum_b (numerator - denominator).
// ---------------------------------------------------------------------------
__global__ __launch_bounds__(256) void crf_reduce_kernel(
    const float* __restrict__ den,
    const float* __restrict__ numemit,
    const float* __restrict__ numtrans,
    float* __restrict__ out)
{
    __shared__ float red[256];
    const int tid = threadIdx.x;
    red[tid] = numemit[tid] + numtrans[tid] - den[tid];
    __syncthreads();
    for (int off = 128; off > 0; off >>= 1) {
        if (tid < off) red[tid] += red[tid + off];
        __syncthreads();
    }
    if (tid == 0) out[0] = red[0];
}

// ---------------------------------------------------------------------------
extern "C" void kernel_launch(void* const* d_in, const int* in_sizes, int n_in,
                              void* d_out, int out_size, void* d_ws, size_t ws_size,
                              hipStream_t stream)
{
    const float* logits = (const float*)d_in[0];
    const int*   tags   = (const int*)  d_in[1];
    const int*   mask   = (const int*)  d_in[2];
    const float* trans  = (const float*)d_in[3];
    const float* startT = (const float*)d_in[4];
    const float* endT   = (const float*)d_in[5];
    float* out = (float*)d_out;

    float* ws       = (float*)d_ws;
    float* den      = ws;                     // 256
    float* numemit  = ws + BSZ;               // 256
    float* numtrans = ws + 2 * BSZ;           // 256
    float* Cf       = ws + 3 * BSZ;           // 256*16
    float* numem    = Cf + BSZ * NC;          // 256*16
    float* rbuf     = numem + BSZ * NC;       // 256*16*64
    float* wbuf     = rbuf + BSZ * NC * NT;   // 256*16*64

    crf_pass1_kernel<<<BSZ * NC, 128, 0, stream>>>(logits, tags, mask, trans,
                                                   startT, rbuf, wbuf, Cf, numem);
    crf_glue_kernel<<<BSZ, 64, 0, stream>>>(rbuf, wbuf, Cf, numem, endT,
                                            den, numemit);
    crf_numer_kernel<<<BSZ, 256, 0, stream>>>(logits, tags, mask, trans,
                                              startT, endT, numtrans);
    crf_reduce_kernel<<<1, 256, 0, stream>>>(den, numemit, numtrans, out);
}

// Round 7
// 105.567 us; speedup vs baseline: 4.5247x; 1.9933x over previous
//
#include <hip/hip_runtime.h>

#define BSZ 256
#define SEQ 2048
#define NT  64
#define NC  64      // chunks per sequence
#define CL  32      // steps per chunk
#define KS  5.0f

typedef __fp16 half2_t __attribute__((ext_vector_type(2)));
typedef __fp16 half4_t __attribute__((ext_vector_type(4)));
typedef float  f32x4_t __attribute__((ext_vector_type(4)));
typedef int    int2_t  __attribute__((ext_vector_type(2)));

static __device__ __forceinline__ float wave_red_sum(float x) {
#pragma unroll
    for (int d = 1; d < 64; d <<= 1) x += __shfl_xor(x, d);
    return x;
}

static __device__ __forceinline__ half4_t pack4(float a, float b, float c, float d) {
    half2_t lo = __builtin_amdgcn_cvt_pkrtz(a, b);
    half2_t hi = __builtin_amdgcn_cvt_pkrtz(c, d);
    int2_t t;
    t.x = __builtin_bit_cast(int, lo);
    t.y = __builtin_bit_cast(int, hi);
    return __builtin_bit_cast(half4_t, t);
}

// ---------------------------------------------------------------------------
// Pass 1 (MFMA): each wave advances 16 runs (16 batches, one chunk, one dir).
// State X[tag][run] (64x16) distributed per v_mfma_f32_16x16x16f16 B-frag:
// lane l holds run = l&15, tags {16*blk + 4*(l>>4) + i}. The mfma D-frag has
// the SAME (lane,reg)->(tag,run) mapping, so step outputs chain into the next
// step's B operand with no cross-lane movement (cvt to f16 only).
// fwd: X' = F ∘ (E^T X); bwd: X' = E (F ∘ X). E-frags (A operand) are
// loop-invariant in registers. Rank-1 contraction over CL=32 steps makes the
// chunk product exactly rank-1 at f32 (kappa^31 ~ 2e-14). Mask=0 steps leave
// X unchanged (exact; note: an entirely-masked chunk would break rank-1).
// ---------------------------------------------------------------------------
__global__ __launch_bounds__(128) void crf_pass1_kernel(
    const float* __restrict__ logits,
    const int*   __restrict__ mask,
    const float* __restrict__ trans,
    const float* __restrict__ startT,
    float* __restrict__ rbuf,    // [BSZ][NC][NT]
    float* __restrict__ wbuf,    // [BSZ][NC][NT] (slot 0 unused)
    float* __restrict__ Cf)      // [BSZ][NC]
{
    const int blk  = blockIdx.x;           // bg*NC + c
    const int c    = blk & (NC - 1);
    const int bg   = blk >> 6;
    const bool fwd = (threadIdx.x >> 6) == 0;
    const int lane = threadIdx.x & 63;
    const int rlo  = lane & 15;
    const int h    = lane >> 4;
    const int batch = bg * 16 + rlo;

    if (!fwd && c == 0) return;

    // A fragments: A[q][kc]; lane l holds A[16q + rlo][16kc + 4h + i], i=0..3
    // fwd: A = E^T  (A[m][k] = exp(trans[k][m]))
    // bwd: A = E    (A[m][k] = exp(trans[m][k]))
    half4_t A[4][4];
#pragma unroll
    for (int q = 0; q < 4; ++q)
#pragma unroll
        for (int kc = 0; kc < 4; ++kc) {
            float e[4];
#pragma unroll
            for (int i = 0; i < 4; ++i) {
                int m = 16 * q + rlo;
                int k = 16 * kc + 4 * h + i;
                e[i] = __expf(fwd ? trans[k * NT + m] : trans[m * NT + k]);
            }
            A[q][kc] = pack4(e[0], e[1], e[2], e[3]);
        }

    const float* __restrict__ Lb  = logits + (size_t)batch * SEQ * NT + 4 * h;
    const int*   __restrict__ mkb = mask + (size_t)batch * SEQ;

    f32x4_t V[4];
    float C = 0.0f;
    int t0, nsteps, dt;

    if (fwd) {
        dt = 1;
        if (c == 0) {
            float mx = -1e30f;
            f32x4_t al[4];
#pragma unroll
            for (int q = 0; q < 4; ++q) {
                f32x4_t em = *(const f32x4_t*)(Lb + 16 * q);   // t = 0
#pragma unroll
                for (int i = 0; i < 4; ++i) {
                    float a = startT[16 * q + 4 * h + i] + em[i];
                    al[q][i] = a;
                    mx = fmaxf(mx, a);
                }
            }
            mx = fmaxf(mx, __shfl_xor(mx, 16));
            mx = fmaxf(mx, __shfl_xor(mx, 32));
            C = mx;
#pragma unroll
            for (int q = 0; q < 4; ++q)
#pragma unroll
                for (int i = 0; i < 4; ++i) V[q][i] = __expf(al[q][i] - mx);
            t0 = 1; nsteps = CL - 1;
        } else {
#pragma unroll
            for (int q = 0; q < 4; ++q)
#pragma unroll
                for (int i = 0; i < 4; ++i) V[q][i] = 1.0f;
            t0 = c * CL; nsteps = CL;
        }
    } else {
        dt = -1;
#pragma unroll
        for (int q = 0; q < 4; ++q)
#pragma unroll
            for (int i = 0; i < 4; ++i) V[q][i] = 1.0f;
        t0 = c * CL + CL - 1; nsteps = CL;
    }

    f32x4_t eb0[4], eb1[4];
    int mtb0, mtb1;
    auto LOAD = [&](int s, f32x4_t (&eb)[4], int& mt) {
        int ss = s > nsteps - 1 ? nsteps - 1 : s;
        int t = t0 + ss * dt;
#pragma unroll
        for (int q = 0; q < 4; ++q)
            eb[q] = *(const f32x4_t*)(Lb + (size_t)t * NT + 16 * q);
        mt = mkb[t];
    };
    LOAD(0, eb0, mtb0);
    LOAD(1, eb1, mtb1);

    auto STEP = [&](int s, f32x4_t (&eb)[4], int& mtref) {
        f32x4_t ecur[4];
        int mt = mtref;
#pragma unroll
        for (int q = 0; q < 4; ++q) ecur[q] = eb[q];
        LOAD(s + 2, eb, mtref);    // prefetch (clamped; redundant at tail)

        half4_t Xh[4];
        if (fwd) {
#pragma unroll
            for (int kc = 0; kc < 4; ++kc)
                Xh[kc] = pack4(V[kc][0], V[kc][1], V[kc][2], V[kc][3]);
        } else {
#pragma unroll
            for (int kc = 0; kc < 4; ++kc) {
                float g0 = __expf(ecur[kc][0] - KS) * V[kc][0];
                float g1 = __expf(ecur[kc][1] - KS) * V[kc][1];
                float g2 = __expf(ecur[kc][2] - KS) * V[kc][2];
                float g3 = __expf(ecur[kc][3] - KS) * V[kc][3];
                Xh[kc] = pack4(g0, g1, g2, g3);
            }
        }

        f32x4_t Y[4];
#pragma unroll
        for (int q = 0; q < 4; ++q) {
            f32x4_t acc = {0.0f, 0.0f, 0.0f, 0.0f};
#pragma unroll
            for (int kc = 0; kc < 4; ++kc)
                acc = __builtin_amdgcn_mfma_f32_16x16x16f16(A[q][kc], Xh[kc], acc, 0, 0, 0);
            Y[q] = acc;
        }

        if (fwd) {
#pragma unroll
            for (int q = 0; q < 4; ++q)
#pragma unroll
                for (int i = 0; i < 4; ++i) {
                    float w = Y[q][i] * __expf(ecur[q][i] - KS);
                    V[q][i] = mt ? w : V[q][i];
                }
            C += mt ? KS : 0.0f;
        } else {
#pragma unroll
            for (int q = 0; q < 4; ++q)
#pragma unroll
                for (int i = 0; i < 4; ++i)
                    V[q][i] = mt ? Y[q][i] : V[q][i];
        }

        if ((s & 7) == 7) {        // renorm (per run: reduce regs + h-groups)
            float mx = V[0][0];
#pragma unroll
            for (int q = 0; q < 4; ++q)
#pragma unroll
                for (int i = 0; i < 4; ++i) mx = fmaxf(mx, V[q][i]);
            mx = fmaxf(mx, __shfl_xor(mx, 16));
            mx = fmaxf(mx, __shfl_xor(mx, 32));
            float inv = 1.0f / mx;
#pragma unroll
            for (int q = 0; q < 4; ++q)
#pragma unroll
                for (int i = 0; i < 4; ++i) V[q][i] *= inv;
            if (fwd) C += __logf(mx);
        }
    };

    int s = 0;
    for (; s + 2 <= nsteps; s += 2) {
        STEP(s, eb0, mtb0);
        STEP(s + 1, eb1, mtb1);
    }
    if (s < nsteps) STEP(s, eb0, mtb0);

    float* out = fwd ? rbuf : wbuf;
    float* op  = out + ((size_t)batch * NC + c) * NT + 4 * h;
#pragma unroll
    for (int q = 0; q < 4; ++q) *(f32x4_t*)(op + 16 * q) = V[q];
    if (fwd && h == 0) Cf[batch * NC + c] = C;
}

// ---------------------------------------------------------------------------
// Glue: log Z = sum Cf + sum_{c>=1}[log(r_{c-1}.w_c) - log(sum w_c)]
//              + log(r_{NC-1}.exp(end))
// ---------------------------------------------------------------------------
__global__ __launch_bounds__(64) void crf_glue_kernel(
    const float* __restrict__ rbuf,
    const float* __restrict__ wbuf,
    const float* __restrict__ Cf,
    const float* __restrict__ endT,
    float* __restrict__ den_out)
{
    const int batch = blockIdx.x;
    const int j     = threadIdx.x;

    const float* rb = rbuf + (size_t)batch * NC * NT;
    const float* wb = wbuf + (size_t)batch * NC * NT;

    float cfsum = Cf[batch * NC + j];   // NC == 64 == wave size
    cfsum = wave_red_sum(cfsum);

    float den = cfsum;
    for (int c = 1; c < NC; ++c) {
        float rprev = rb[(c - 1) * NT + j];
        float wc    = wb[c * NT + j];
        float dot = wave_red_sum(rprev * wc);
        float rho = wave_red_sum(wc);
        den += __logf(dot) - __logf(rho);
    }
    float fin = wave_red_sum(rb[(NC - 1) * NT + j] * __expf(endT[j]));
    den += __logf(fin);

    if (j == 0) den_out[batch] = den;
}

// ---------------------------------------------------------------------------
// Numerator: start/end/transition terms + emission gather (incl. last step).
// ---------------------------------------------------------------------------
__global__ __launch_bounds__(256) void crf_numer_kernel(
    const float* __restrict__ logits,
    const int*   __restrict__ tags,
    const int*   __restrict__ mask,
    const float* __restrict__ trans,
    const float* __restrict__ startT,
    const float* __restrict__ endT,
    float* __restrict__ numtrans_out)
{
    const int b   = blockIdx.x;
    const int tid = threadIdx.x;

    __shared__ float st[NT * NT];
    __shared__ float redf[256];
    __shared__ int   redi[256];

    for (int i = tid; i < NT * NT; i += 256) st[i] = trans[i];
    __syncthreads();

    const int*   __restrict__ tg = tags + (size_t)b * SEQ;
    const int*   __restrict__ mk = mask + (size_t)b * SEQ;
    const float* __restrict__ Lr = logits + (size_t)b * SEQ * NT;

    float acc = 0.0f;
    int   cnt = 0;
    for (int t = tid; t < SEQ; t += 256) {
        int mt  = mk[t];
        cnt += mt;
        int tgt = tg[t] * mt;
        if (t < SEQ - 1) {
            int m1 = mk[t + 1];
            acc += st[tgt * NT + tg[t + 1] * m1] * (float)m1;  // transition
            acc += Lr[t * NT + tgt] * (float)mt;               // emission
        }
    }
    redf[tid] = acc;
    redi[tid] = cnt;
    __syncthreads();
    for (int off = 128; off > 0; off >>= 1) {
        if (tid < off) {
            redf[tid] += redf[tid + off];
            redi[tid] += redi[tid + off];
        }
        __syncthreads();
    }

    if (tid == 0) {
        int   last_idx = redi[0] - 1;
        int   m_last   = mk[SEQ - 1];
        int   tag0     = tg[0] * mk[0];
        int   last_tag = tg[last_idx] * mk[last_idx];
        float r = redf[0] + startT[tag0] + endT[last_tag];
        r += Lr[(size_t)(SEQ - 1) * NT + last_tag] * (float)m_last;
        numtrans_out[b] = r;
    }
}

// ---------------------------------------------------------------------------
// Final scalar reduction: out = sum_b (numerator - denominator).
// ---------------------------------------------------------------------------
__global__ __launch_bounds__(256) void crf_reduce_kernel(
    const float* __restrict__ den,
    const float* __restrict__ numtrans,
    float* __restrict__ out)
{
    __shared__ float red[256];
    const int tid = threadIdx.x;
    red[tid] = numtrans[tid] - den[tid];
    __syncthreads();
    for (int off = 128; off > 0; off >>= 1) {
        if (tid < off) red[tid] += red[tid + off];
        __syncthreads();
    }
    if (tid == 0) out[0] = red[0];
}

// ---------------------------------------------------------------------------
extern "C" void kernel_launch(void* const* d_in, const int* in_sizes, int n_in,
                              void* d_out, int out_size, void* d_ws, size_t ws_size,
                              hipStream_t stream)
{
    const float* logits = (const float*)d_in[0];
    const int*   tags   = (const int*)  d_in[1];
    const int*   mask   = (const int*)  d_in[2];
    const float* trans  = (const float*)d_in[3];
    const float* startT = (const float*)d_in[4];
    const float* endT   = (const float*)d_in[5];
    float* out = (float*)d_out;

    float* ws       = (float*)d_ws;
    float* den      = ws;                     // 256
    float* numtrans = ws + BSZ;               // 256
    float* Cf       = ws + 2 * BSZ;           // 256*64
    float* rbuf     = Cf + BSZ * NC;          // 256*64*64
    float* wbuf     = rbuf + BSZ * NC * NT;   // 256*64*64

    crf_pass1_kernel<<<(BSZ / 16) * NC, 128, 0, stream>>>(logits, mask, trans,
                                                          startT, rbuf, wbuf, Cf);
    crf_glue_kernel<<<BSZ, 64, 0, stream>>>(rbuf, wbuf, Cf, endT, den);
    crf_numer_kernel<<<BSZ, 256, 0, stream>>>(logits, tags, mask, trans,
                                              startT, endT, numtrans);
    crf_reduce_kernel<<<1, 256, 0, stream>>>(den, numtrans, out);
}

// Round 8
// 96.714 us; speedup vs baseline: 4.9389x; 1.0915x over previous
//
#include <hip/hip_runtime.h>

#define BSZ 256
#define SEQ 2048
#define NT  64
#define KS  5.0f

typedef __fp16 half2_t __attribute__((ext_vector_type(2)));
typedef __fp16 half4_t __attribute__((ext_vector_type(4)));
typedef float  f32x4_t __attribute__((ext_vector_type(4)));
typedef int    int2_t  __attribute__((ext_vector_type(2)));

static __device__ __forceinline__ float wave_red_sum(float x) {
#pragma unroll
    for (int d = 1; d < 64; d <<= 1) x += __shfl_xor(x, d);
    return x;
}

static __device__ __forceinline__ half4_t pack4(float a, float b, float c, float d) {
    half2_t lo = __builtin_amdgcn_cvt_pkrtz(a, b);
    half2_t hi = __builtin_amdgcn_cvt_pkrtz(c, d);
    int2_t t;
    t.x = __builtin_bit_cast(int, lo);
    t.y = __builtin_bit_cast(int, hi);
    return __builtin_bit_cast(half4_t, t);
}

// ---------------------------------------------------------------------------
// Fat kernel: blocks [0, P1B) run pass1 (chunked scan, MFMA); blocks
// [P1B, P1B+BSZ) run the numerator gather. Both 128 threads.
//
// Pass1: wave 0 = forward chunk run, wave 1 = backward chunk run, 16 batches
// per wave as MFMA B/D fragments (see R6 comment). X' = F∘(E^T X) fwd,
// X' = E(F∘X) bwd; D-frag feeds next B-frag with no cross-lane movement.
// ---------------------------------------------------------------------------
template<int CL>
__global__ __launch_bounds__(128) void crf_fat_kernel(
    const float* __restrict__ logits,
    const int*   __restrict__ tags,
    const int*   __restrict__ mask,
    const float* __restrict__ trans,
    const float* __restrict__ startT,
    const float* __restrict__ endT,
    float* __restrict__ rbuf,    // [BSZ][NCc][NT]
    float* __restrict__ wbuf,    // [BSZ][NCc][NT] (slot 0 unused)
    float* __restrict__ Cf,      // [BSZ][NCc]
    float* __restrict__ numtrans)
{
    constexpr int NCc = SEQ / CL;
    constexpr int P1B = (BSZ / 16) * NCc;

    if ((int)blockIdx.x >= P1B) {
        // ---------------- numerator branch ----------------
        const int b   = blockIdx.x - P1B;
        const int tid = threadIdx.x;
        __shared__ float redf[128];
        __shared__ int   redi[128];

        const int*   __restrict__ tg = tags + (size_t)b * SEQ;
        const int*   __restrict__ mk = mask + (size_t)b * SEQ;
        const float* __restrict__ Lr = logits + (size_t)b * SEQ * NT;

        float acc = 0.0f;
        int   cnt = 0;
        for (int t = tid; t < SEQ; t += 128) {
            int mt  = mk[t];
            cnt += mt;
            int tgt = tg[t] * mt;
            if (t < SEQ - 1) {
                int m1 = mk[t + 1];
                acc += trans[tgt * NT + tg[t + 1] * m1] * (float)m1;
                acc += Lr[t * NT + tgt] * (float)mt;
            }
        }
        redf[tid] = acc;
        redi[tid] = cnt;
        __syncthreads();
        for (int off = 64; off > 0; off >>= 1) {
            if (tid < off) {
                redf[tid] += redf[tid + off];
                redi[tid] += redi[tid + off];
            }
            __syncthreads();
        }
        if (tid == 0) {
            int   last_idx = redi[0] - 1;
            int   m_last   = mk[SEQ - 1];
            int   tag0     = tg[0] * mk[0];
            int   last_tag = tg[last_idx] * mk[last_idx];
            float r = redf[0] + startT[tag0] + endT[last_tag];
            r += Lr[(size_t)(SEQ - 1) * NT + last_tag] * (float)m_last;
            numtrans[b] = r;
        }
        return;
    }

    // ---------------- pass1 branch ----------------
    const int blk  = blockIdx.x;
    const int c    = blk & (NCc - 1);
    const int bg   = blk / NCc;
    const bool fwd = (threadIdx.x >> 6) == 0;
    const int lane = threadIdx.x & 63;
    const int rlo  = lane & 15;
    const int h    = lane >> 4;
    const int batch = bg * 16 + rlo;

    if (!fwd && c == 0) return;

    // A fragments: fwd A = E^T, bwd A = E. Lane l: A[16q+rlo][16kc+4h+i]
    half4_t A[4][4];
#pragma unroll
    for (int q = 0; q < 4; ++q)
#pragma unroll
        for (int kc = 0; kc < 4; ++kc) {
            float e[4];
#pragma unroll
            for (int i = 0; i < 4; ++i) {
                int m = 16 * q + rlo;
                int k = 16 * kc + 4 * h + i;
                e[i] = __expf(fwd ? trans[k * NT + m] : trans[m * NT + k]);
            }
            A[q][kc] = pack4(e[0], e[1], e[2], e[3]);
        }

    const float* __restrict__ Lb  = logits + (size_t)batch * SEQ * NT + 4 * h;
    const int*   __restrict__ mkb = mask + (size_t)batch * SEQ;

    f32x4_t V[4];
    float C = 0.0f;
    int t0, nsteps, dt;

    if (fwd) {
        dt = 1;
        if (c == 0) {
            float mx = -1e30f;
            f32x4_t al[4];
#pragma unroll
            for (int q = 0; q < 4; ++q) {
                f32x4_t em = *(const f32x4_t*)(Lb + 16 * q);   // t = 0
#pragma unroll
                for (int i = 0; i < 4; ++i) {
                    float a = startT[16 * q + 4 * h + i] + em[i];
                    al[q][i] = a;
                    mx = fmaxf(mx, a);
                }
            }
            mx = fmaxf(mx, __shfl_xor(mx, 16));
            mx = fmaxf(mx, __shfl_xor(mx, 32));
            C = mx;
#pragma unroll
            for (int q = 0; q < 4; ++q)
#pragma unroll
                for (int i = 0; i < 4; ++i) V[q][i] = __expf(al[q][i] - mx);
            t0 = 1; nsteps = CL - 1;
        } else {
#pragma unroll
            for (int q = 0; q < 4; ++q)
#pragma unroll
                for (int i = 0; i < 4; ++i) V[q][i] = 1.0f;
            t0 = c * CL; nsteps = CL;
        }
    } else {
        dt = -1;
#pragma unroll
        for (int q = 0; q < 4; ++q)
#pragma unroll
            for (int i = 0; i < 4; ++i) V[q][i] = 1.0f;
        t0 = c * CL + CL - 1; nsteps = CL;
    }

    f32x4_t eb0[4], eb1[4];
    int mtb0, mtb1;
    auto LOAD = [&](int s, f32x4_t (&eb)[4], int& mt) {
        int ss = s > nsteps - 1 ? nsteps - 1 : s;
        int t = t0 + ss * dt;
#pragma unroll
        for (int q = 0; q < 4; ++q)
            eb[q] = *(const f32x4_t*)(Lb + (size_t)t * NT + 16 * q);
        mt = mkb[t];
    };
    LOAD(0, eb0, mtb0);
    LOAD(1, eb1, mtb1);

    auto STEP = [&](int s, f32x4_t (&eb)[4], int& mtref) {
        f32x4_t ecur[4];
        int mt = mtref;
#pragma unroll
        for (int q = 0; q < 4; ++q) ecur[q] = eb[q];
        LOAD(s + 2, eb, mtref);    // prefetch (clamped; redundant at tail)

        half4_t Xh[4];
        if (fwd) {
#pragma unroll
            for (int kc = 0; kc < 4; ++kc)
                Xh[kc] = pack4(V[kc][0], V[kc][1], V[kc][2], V[kc][3]);
        } else {
#pragma unroll
            for (int kc = 0; kc < 4; ++kc) {
                float g0 = __expf(ecur[kc][0] - KS) * V[kc][0];
                float g1 = __expf(ecur[kc][1] - KS) * V[kc][1];
                float g2 = __expf(ecur[kc][2] - KS) * V[kc][2];
                float g3 = __expf(ecur[kc][3] - KS) * V[kc][3];
                Xh[kc] = pack4(g0, g1, g2, g3);
            }
        }

        f32x4_t Y[4];
#pragma unroll
        for (int q = 0; q < 4; ++q) {
            f32x4_t acc = {0.0f, 0.0f, 0.0f, 0.0f};
#pragma unroll
            for (int kc = 0; kc < 4; ++kc)
                acc = __builtin_amdgcn_mfma_f32_16x16x16f16(A[q][kc], Xh[kc], acc, 0, 0, 0);
            Y[q] = acc;
        }

        if (fwd) {
#pragma unroll
            for (int q = 0; q < 4; ++q)
#pragma unroll
                for (int i = 0; i < 4; ++i) {
                    float w = Y[q][i] * __expf(ecur[q][i] - KS);
                    V[q][i] = mt ? w : V[q][i];
                }
            C += mt ? KS : 0.0f;
        } else {
#pragma unroll
            for (int q = 0; q < 4; ++q)
#pragma unroll
                for (int i = 0; i < 4; ++i)
                    V[q][i] = mt ? Y[q][i] : V[q][i];
        }

        if ((s & 7) == 7) {        // renorm
            float mx = V[0][0];
#pragma unroll
            for (int q = 0; q < 4; ++q)
#pragma unroll
                for (int i = 0; i < 4; ++i) mx = fmaxf(mx, V[q][i]);
            mx = fmaxf(mx, __shfl_xor(mx, 16));
            mx = fmaxf(mx, __shfl_xor(mx, 32));
            float inv = 1.0f / mx;
#pragma unroll
            for (int q = 0; q < 4; ++q)
#pragma unroll
                for (int i = 0; i < 4; ++i) V[q][i] *= inv;
            if (fwd) C += __logf(mx);
        }
    };

    int s = 0;
    for (; s + 2 <= nsteps; s += 2) {
        STEP(s, eb0, mtb0);
        STEP(s + 1, eb1, mtb1);
    }
    if (s < nsteps) STEP(s, eb0, mtb0);

    float* outp = fwd ? rbuf : wbuf;
    float* op   = outp + ((size_t)batch * NCc + c) * NT + 4 * h;
#pragma unroll
    for (int q = 0; q < 4; ++q) *(f32x4_t*)(op + 16 * q) = V[q];
    if (fwd && h == 0) Cf[batch * NCc + c] = C;
}

// ---------------------------------------------------------------------------
// Glue (4 waves): log Z = sum Cf + sum_{c>=1}[log(r_{c-1}.w_c) - log(sum w_c)]
//                + log(r_{NCc-1}.exp(end))
// ---------------------------------------------------------------------------
template<int CL>
__global__ __launch_bounds__(256) void crf_glue_kernel(
    const float* __restrict__ rbuf,
    const float* __restrict__ wbuf,
    const float* __restrict__ Cf,
    const float* __restrict__ endT,
    float* __restrict__ den_out)
{
    constexpr int NCc = SEQ / CL;
    const int batch = blockIdx.x;
    const int tid   = threadIdx.x;
    const int lane  = tid & 63;
    const int w     = tid >> 6;

    const float* rb = rbuf + (size_t)batch * NCc * NT;
    const float* wb = wbuf + (size_t)batch * NCc * NT;

    float x = 0.0f;
    for (int c = tid; c < NCc; c += 256) x += Cf[batch * NCc + c];

    float part = 0.0f;
    for (int c = 1 + w; c < NCc; c += 4) {
        float rprev = rb[(c - 1) * NT + lane];
        float wc    = wb[c * NT + lane];
        float dot = wave_red_sum(rprev * wc);
        float rho = wave_red_sum(wc);
        part += __logf(dot) - __logf(rho);
    }
    if (lane == 0) x += part;
    if (w == 0) {
        float fin = wave_red_sum(rb[(NCc - 1) * NT + lane] * __expf(endT[lane]));
        if (lane == 0) x += __logf(fin);
    }

    __shared__ float sred[256];
    sred[tid] = x;
    __syncthreads();
    for (int off = 128; off > 0; off >>= 1) {
        if (tid < off) sred[tid] += sred[tid + off];
        __syncthreads();
    }
    if (tid == 0) den_out[batch] = sred[0];
}

// ---------------------------------------------------------------------------
// Final scalar reduction: out = sum_b (numerator - denominator).
// ---------------------------------------------------------------------------
__global__ __launch_bounds__(256) void crf_reduce_kernel(
    const float* __restrict__ den,
    const float* __restrict__ numtrans,
    float* __restrict__ out)
{
    __shared__ float red[256];
    const int tid = threadIdx.x;
    red[tid] = numtrans[tid] - den[tid];
    __syncthreads();
    for (int off = 128; off > 0; off >>= 1) {
        if (tid < off) red[tid] += red[tid + off];
        __syncthreads();
    }
    if (tid == 0) out[0] = red[0];
}

// ---------------------------------------------------------------------------
extern "C" void kernel_launch(void* const* d_in, const int* in_sizes, int n_in,
                              void* d_out, int out_size, void* d_ws, size_t ws_size,
                              hipStream_t stream)
{
    const float* logits = (const float*)d_in[0];
    const int*   tags   = (const int*)  d_in[1];
    const int*   mask   = (const int*)  d_in[2];
    const float* trans  = (const float*)d_in[3];
    const float* startT = (const float*)d_in[4];
    const float* endT   = (const float*)d_in[5];
    float* out = (float*)d_out;

    float* ws = (float*)d_ws;

    // preferred config: CL=16 (NC=128) for 2x occupancy
    {
        constexpr int CL16 = 16;
        constexpr int NC16 = SEQ / CL16;
        size_t need = ((size_t)2 * BSZ + (size_t)BSZ * NC16 +
                       2 * (size_t)BSZ * NC16 * NT) * sizeof(float);
        if (ws_size >= need) {
            float* den      = ws;
            float* numtrans = ws + BSZ;
            float* Cf       = ws + 2 * BSZ;
            float* rbuf     = Cf + BSZ * NC16;
            float* wbuf     = rbuf + (size_t)BSZ * NC16 * NT;
            crf_fat_kernel<CL16><<<(BSZ / 16) * NC16 + BSZ, 128, 0, stream>>>(
                logits, tags, mask, trans, startT, endT, rbuf, wbuf, Cf, numtrans);
            crf_glue_kernel<CL16><<<BSZ, 256, 0, stream>>>(rbuf, wbuf, Cf, endT, den);
            crf_reduce_kernel<<<1, 256, 0, stream>>>(den, numtrans, out);
            return;
        }
    }
    // fallback: CL=32 (NC=64), fits in 8.5 MB (proven R6)
    {
        constexpr int CL32 = 32;
        constexpr int NC32 = SEQ / CL32;
        float* den      = ws;
        float* numtrans = ws + BSZ;
        float* Cf       = ws + 2 * BSZ;
        float* rbuf     = Cf + BSZ * NC32;
        float* wbuf     = rbuf + (size_t)BSZ * NC32 * NT;
        crf_fat_kernel<CL32><<<(BSZ / 16) * NC32 + BSZ, 128, 0, stream>>>(
            logits, tags, mask, trans, startT, endT, rbuf, wbuf, Cf, numtrans);
        crf_glue_kernel<CL32><<<BSZ, 256, 0, stream>>>(rbuf, wbuf, Cf, endT, den);
        crf_reduce_kernel<<<1, 256, 0, stream>>>(den, numtrans, out);
    }
}

// Round 9
// 87.913 us; speedup vs baseline: 5.4333x; 1.1001x over previous
//
#include <hip/hip_runtime.h>

#define BSZ 256
#define SEQ 2048
#define NT  64
#define KS  5.0f

typedef __fp16 half2_t __attribute__((ext_vector_type(2)));
typedef __fp16 half4_t __attribute__((ext_vector_type(4)));
typedef float  f32x4_t __attribute__((ext_vector_type(4)));
typedef int    int2_t  __attribute__((ext_vector_type(2)));

static __device__ __forceinline__ float wave_red_sum(float x) {
#pragma unroll
    for (int d = 1; d < 64; d <<= 1) x += __shfl_xor(x, d);
    return x;
}

static __device__ __forceinline__ half4_t pack4(float a, float b, float c, float d) {
    half2_t lo = __builtin_amdgcn_cvt_pkrtz(a, b);
    half2_t hi = __builtin_amdgcn_cvt_pkrtz(c, d);
    int2_t t;
    t.x = __builtin_bit_cast(int, lo);
    t.y = __builtin_bit_cast(int, hi);
    return __builtin_bit_cast(half4_t, t);
}

// ---------------------------------------------------------------------------
// Fat kernel. Pass1 blocks: 2 waves, wave 0 = forward, wave 1 = backward.
// Each wave advances TWO chunks (2p, 2p+1) of 16 batches as two independent
// dependence chains, interleaved per step for ILP (chain A's MFMA latency is
// hidden under chain B's issue and vice versa). A-fragments (E or E^T as f16)
// are shared by both chains. D-frag -> next-step B-frag needs no cross-lane
// movement (same (lane,reg)->(tag,run) map); see R6.
// fwd: X' = F ∘ (E^T X); bwd: X' = E (F ∘ X).
// ---------------------------------------------------------------------------
template<int CL>
__global__ __launch_bounds__(128) void crf_fat_kernel(
    const float* __restrict__ logits,
    const int*   __restrict__ tags,
    const int*   __restrict__ mask,
    const float* __restrict__ trans,
    const float* __restrict__ startT,
    const float* __restrict__ endT,
    float* __restrict__ rbuf,    // [BSZ][NCc][NT]
    float* __restrict__ wbuf,    // [BSZ][NCc][NT] (slot 0 unused)
    float* __restrict__ Cf,      // [BSZ][NCc]
    float* __restrict__ numtrans)
{
    constexpr int NCc   = SEQ / CL;
    constexpr int PAIRS = NCc / 2;
    constexpr int P1B   = (BSZ / 16) * PAIRS;

    if ((int)blockIdx.x >= P1B) {
        // ---------------- numerator branch ----------------
        const int b   = blockIdx.x - P1B;
        const int tid = threadIdx.x;
        __shared__ float redf[128];
        __shared__ int   redi[128];

        const int*   __restrict__ tg = tags + (size_t)b * SEQ;
        const int*   __restrict__ mk = mask + (size_t)b * SEQ;
        const float* __restrict__ Lr = logits + (size_t)b * SEQ * NT;

        float acc = 0.0f;
        int   cnt = 0;
        for (int t = tid; t < SEQ; t += 128) {
            int mt  = mk[t];
            cnt += mt;
            int tgt = tg[t] * mt;
            if (t < SEQ - 1) {
                int m1 = mk[t + 1];
                acc += trans[tgt * NT + tg[t + 1] * m1] * (float)m1;
                acc += Lr[t * NT + tgt] * (float)mt;
            }
        }
        redf[tid] = acc;
        redi[tid] = cnt;
        __syncthreads();
        for (int off = 64; off > 0; off >>= 1) {
            if (tid < off) {
                redf[tid] += redf[tid + off];
                redi[tid] += redi[tid + off];
            }
            __syncthreads();
        }
        if (tid == 0) {
            int   last_idx = redi[0] - 1;
            int   m_last   = mk[SEQ - 1];
            int   tag0     = tg[0] * mk[0];
            int   last_tag = tg[last_idx] * mk[last_idx];
            float r = redf[0] + startT[tag0] + endT[last_tag];
            r += Lr[(size_t)(SEQ - 1) * NT + last_tag] * (float)m_last;
            numtrans[b] = r;
        }
        return;
    }

    // ---------------- pass1 branch ----------------
    const int blk  = blockIdx.x;
    const int pr   = blk % PAIRS;
    const int bg   = blk / PAIRS;
    const int cA   = 2 * pr;
    const int cB   = 2 * pr + 1;
    const bool fwd = (threadIdx.x >> 6) == 0;
    const int lane = threadIdx.x & 63;
    const int rlo  = lane & 15;
    const int h    = lane >> 4;
    const int batch = bg * 16 + rlo;

    // A fragments: fwd A = E^T, bwd A = E. Lane l: A[16q+rlo][16kc+4h+i]
    half4_t A[4][4];
#pragma unroll
    for (int q = 0; q < 4; ++q)
#pragma unroll
        for (int kc = 0; kc < 4; ++kc) {
            float e[4];
#pragma unroll
            for (int i = 0; i < 4; ++i) {
                int m = 16 * q + rlo;
                int k = 16 * kc + 4 * h + i;
                e[i] = __expf(fwd ? trans[k * NT + m] : trans[m * NT + k]);
            }
            A[q][kc] = pack4(e[0], e[1], e[2], e[3]);
        }

    const float* __restrict__ Lb  = logits + (size_t)batch * SEQ * NT + 4 * h;
    const int*   __restrict__ mkb = mask + (size_t)batch * SEQ;

    const int dt = fwd ? 1 : -1;

    f32x4_t VA[4], VB[4];
    float CcA = 0.0f, CcB = 0.0f;
    int t0A, nA, t0B, nB;

#pragma unroll
    for (int q = 0; q < 4; ++q)
#pragma unroll
        for (int i = 0; i < 4; ++i) { VA[q][i] = 1.0f; VB[q][i] = 1.0f; }

    if (fwd) {
        if (cA == 0) {
            float mx = -1e30f;
            f32x4_t al[4];
#pragma unroll
            for (int q = 0; q < 4; ++q) {
                f32x4_t em = *(const f32x4_t*)(Lb + 16 * q);   // t = 0
#pragma unroll
                for (int i = 0; i < 4; ++i) {
                    float a = startT[16 * q + 4 * h + i] + em[i];
                    al[q][i] = a;
                    mx = fmaxf(mx, a);
                }
            }
            mx = fmaxf(mx, __shfl_xor(mx, 16));
            mx = fmaxf(mx, __shfl_xor(mx, 32));
            CcA = mx;
#pragma unroll
            for (int q = 0; q < 4; ++q)
#pragma unroll
                for (int i = 0; i < 4; ++i) VA[q][i] = __expf(al[q][i] - mx);
            t0A = 1; nA = CL - 1;
        } else {
            t0A = cA * CL; nA = CL;
        }
        t0B = cB * CL; nB = CL;
    } else {
        if (cA == 0) { t0A = 0; nA = 0; }
        else         { t0A = cA * CL + CL - 1; nA = CL; }
        t0B = cB * CL + CL - 1; nB = CL;
    }

    auto LOADC = [&](int t, f32x4_t (&eb)[4], int& mt) {
#pragma unroll
        for (int q = 0; q < 4; ++q)
            eb[q] = *(const f32x4_t*)(Lb + (size_t)t * NT + 16 * q);
        mt = mkb[t];
    };

    f32x4_t ebA[4], ebB[4];
    int mA = 0, mB = 0;
    if (nA > 0) LOADC(t0A, ebA, mA);
    LOADC(t0B, ebB, mB);

    auto STEP = [&](f32x4_t (&V)[4], float& C, f32x4_t (&eb)[4], int& mref,
                    int t0c, int n, int s) {
        f32x4_t ecur[4];
        int mt = mref;
#pragma unroll
        for (int q = 0; q < 4; ++q) ecur[q] = eb[q];
        int sn = (s + 1 < n) ? s + 1 : n - 1;    // clamped prefetch
        LOADC(t0c + sn * dt, eb, mref);

        half4_t Xh[4];
        if (fwd) {
#pragma unroll
            for (int kc = 0; kc < 4; ++kc)
                Xh[kc] = pack4(V[kc][0], V[kc][1], V[kc][2], V[kc][3]);
        } else {
#pragma unroll
            for (int kc = 0; kc < 4; ++kc) {
                float g0 = __expf(ecur[kc][0] - KS) * V[kc][0];
                float g1 = __expf(ecur[kc][1] - KS) * V[kc][1];
                float g2 = __expf(ecur[kc][2] - KS) * V[kc][2];
                float g3 = __expf(ecur[kc][3] - KS) * V[kc][3];
                Xh[kc] = pack4(g0, g1, g2, g3);
            }
        }

        f32x4_t Y[4];
#pragma unroll
        for (int q = 0; q < 4; ++q) {
            f32x4_t acc = {0.0f, 0.0f, 0.0f, 0.0f};
#pragma unroll
            for (int kc = 0; kc < 4; ++kc)
                acc = __builtin_amdgcn_mfma_f32_16x16x16f16(A[q][kc], Xh[kc], acc, 0, 0, 0);
            Y[q] = acc;
        }

        if (fwd) {
#pragma unroll
            for (int q = 0; q < 4; ++q)
#pragma unroll
                for (int i = 0; i < 4; ++i) {
                    float w = Y[q][i] * __expf(ecur[q][i] - KS);
                    V[q][i] = mt ? w : V[q][i];
                }
            C += mt ? KS : 0.0f;
        } else {
#pragma unroll
            for (int q = 0; q < 4; ++q)
#pragma unroll
                for (int i = 0; i < 4; ++i)
                    V[q][i] = mt ? Y[q][i] : V[q][i];
        }
    };

    auto RENORM = [&](f32x4_t (&V)[4], float& C) {
        float mx = V[0][0];
#pragma unroll
        for (int q = 0; q < 4; ++q)
#pragma unroll
            for (int i = 0; i < 4; ++i) mx = fmaxf(mx, V[q][i]);
        mx = fmaxf(mx, __shfl_xor(mx, 16));
        mx = fmaxf(mx, __shfl_xor(mx, 32));
        float inv = 1.0f / mx;
#pragma unroll
        for (int q = 0; q < 4; ++q)
#pragma unroll
            for (int i = 0; i < 4; ++i) V[q][i] *= inv;
        if (fwd) C += __logf(mx);
    };

    // interleaved dual-chain loop
    for (int s = 0; s < CL; ++s) {
        if (s < nA) STEP(VA, CcA, ebA, mA, t0A, nA, s);
        if (s < nB) STEP(VB, CcB, ebB, mB, t0B, nB, s);
        if ((s & 7) == 7) {
            if (s < nA || nA == CL - 1) RENORM(VA, CcA);  // fwd c0: renorm at s=7 only
            RENORM(VB, CcB);
        }
    }

    float* outp = fwd ? rbuf : wbuf;
    if (nA > 0 || fwd) {
        float* opA = outp + ((size_t)batch * NCc + cA) * NT + 4 * h;
#pragma unroll
        for (int q = 0; q < 4; ++q) *(f32x4_t*)(opA + 16 * q) = VA[q];
    }
    {
        float* opB = outp + ((size_t)batch * NCc + cB) * NT + 4 * h;
#pragma unroll
        for (int q = 0; q < 4; ++q) *(f32x4_t*)(opB + 16 * q) = VB[q];
    }
    if (fwd && h == 0) {
        Cf[batch * NCc + cA] = CcA;
        Cf[batch * NCc + cB] = CcB;
    }
}

// ---------------------------------------------------------------------------
// Glue (4 waves): log Z = sum Cf + sum_{c>=1}[log(r_{c-1}.w_c) - log(sum w_c)]
//                + log(r_{NCc-1}.exp(end))
// ---------------------------------------------------------------------------
template<int CL>
__global__ __launch_bounds__(256) void crf_glue_kernel(
    const float* __restrict__ rbuf,
    const float* __restrict__ wbuf,
    const float* __restrict__ Cf,
    const float* __restrict__ endT,
    float* __restrict__ den_out)
{
    constexpr int NCc = SEQ / CL;
    const int batch = blockIdx.x;
    const int tid   = threadIdx.x;
    const int lane  = tid & 63;
    const int w     = tid >> 6;

    const float* rb = rbuf + (size_t)batch * NCc * NT;
    const float* wb = wbuf + (size_t)batch * NCc * NT;

    float x = 0.0f;
    for (int c = tid; c < NCc; c += 256) x += Cf[batch * NCc + c];

    float part = 0.0f;
    for (int c = 1 + w; c < NCc; c += 4) {
        float rprev = rb[(c - 1) * NT + lane];
        float wc    = wb[c * NT + lane];
        float dot = wave_red_sum(rprev * wc);
        float rho = wave_red_sum(wc);
        part += __logf(dot) - __logf(rho);
    }
    if (lane == 0) x += part;
    if (w == 0) {
        float fin = wave_red_sum(rb[(NCc - 1) * NT + lane] * __expf(endT[lane]));
        if (lane == 0) x += __logf(fin);
    }

    __shared__ float sred[256];
    sred[tid] = x;
    __syncthreads();
    for (int off = 128; off > 0; off >>= 1) {
        if (tid < off) sred[tid] += sred[tid + off];
        __syncthreads();
    }
    if (tid == 0) den_out[batch] = sred[0];
}

// ---------------------------------------------------------------------------
// Final scalar reduction: out = sum_b (numerator - denominator).
// ---------------------------------------------------------------------------
__global__ __launch_bounds__(256) void crf_reduce_kernel(
    const float* __restrict__ den,
    const float* __restrict__ numtrans,
    float* __restrict__ out)
{
    __shared__ float red[256];
    const int tid = threadIdx.x;
    red[tid] = numtrans[tid] - den[tid];
    __syncthreads();
    for (int off = 128; off > 0; off >>= 1) {
        if (tid < off) red[tid] += red[tid + off];
        __syncthreads();
    }
    if (tid == 0) out[0] = red[0];
}

// ---------------------------------------------------------------------------
extern "C" void kernel_launch(void* const* d_in, const int* in_sizes, int n_in,
                              void* d_out, int out_size, void* d_ws, size_t ws_size,
                              hipStream_t stream)
{
    const float* logits = (const float*)d_in[0];
    const int*   tags   = (const int*)  d_in[1];
    const int*   mask   = (const int*)  d_in[2];
    const float* trans  = (const float*)d_in[3];
    const float* startT = (const float*)d_in[4];
    const float* endT   = (const float*)d_in[5];
    float* out = (float*)d_out;

    float* ws = (float*)d_ws;

    // preferred config: CL=16 (NC=128)
    {
        constexpr int CL16 = 16;
        constexpr int NC16 = SEQ / CL16;
        size_t need = ((size_t)2 * BSZ + (size_t)BSZ * NC16 +
                       2 * (size_t)BSZ * NC16 * NT) * sizeof(float);
        if (ws_size >= need) {
            float* den      = ws;
            float* numtrans = ws + BSZ;
            float* Cf       = ws + 2 * BSZ;
            float* rbuf     = Cf + BSZ * NC16;
            float* wbuf     = rbuf + (size_t)BSZ * NC16 * NT;
            crf_fat_kernel<CL16><<<(BSZ / 16) * (NC16 / 2) + BSZ, 128, 0, stream>>>(
                logits, tags, mask, trans, startT, endT, rbuf, wbuf, Cf, numtrans);
            crf_glue_kernel<CL16><<<BSZ, 256, 0, stream>>>(rbuf, wbuf, Cf, endT, den);
            crf_reduce_kernel<<<1, 256, 0, stream>>>(den, numtrans, out);
            return;
        }
    }
    // fallback: CL=32 (NC=64), fits in 8.5 MB (proven R6)
    {
        constexpr int CL32 = 32;
        constexpr int NC32 = SEQ / CL32;
        float* den      = ws;
        float* numtrans = ws + BSZ;
        float* Cf       = ws + 2 * BSZ;
        float* rbuf     = Cf + BSZ * NC32;
        float* wbuf     = rbuf + (size_t)BSZ * NC32 * NT;
        crf_fat_kernel<CL32><<<(BSZ / 16) * (NC32 / 2) + BSZ, 128, 0, stream>>>(
            logits, tags, mask, trans, startT, endT, rbuf, wbuf, Cf, numtrans);
        crf_glue_kernel<CL32><<<BSZ, 256, 0, stream>>>(rbuf, wbuf, Cf, endT, den);
        crf_reduce_kernel<<<1, 256, 0, stream>>>(den, numtrans, out);
    }
}